// Round 1
// baseline (203.659 us; speedup 1.0000x reference)
//
#include <hip/hip_runtime.h>
#include <math.h>

#define BS 16
#define SS 2048
#define HH 1024
#define DD 32
#define CC 8
#define LL 3

// One block per (b,d) span. 256 threads, each owns 4 contiguous cols (float4).
__global__ __launch_bounds__(256) void pool_logits_kernel(
    const float* __restrict__ enc,   // (BS,S,H)
    const float* __restrict__ W,     // (C,H,L)
    const float* __restrict__ bias,  // (C,L)
    const int*   __restrict__ head,  // (BS,D)
    const int*   __restrict__ tail,  // (BS,D)
    const int*   __restrict__ dt,    // (BS,D)
    float* __restrict__ logits)      // (BS,D,L)
{
    const int bd = blockIdx.x;            // 0..BS*DD-1
    const int b  = bd / DD;
    const int s0 = head[bd] + 1;
    const int s1 = tail[bd];
    const int c  = dt[bd];
    const int tid = threadIdx.x;
    const int col = tid * 4;

    const float* base = enc + ((size_t)b * SS) * HH + col;

    float4 a0 = make_float4(0.f, 0.f, 0.f, 0.f);
    float4 a1 = a0, a2 = a0, a3 = a0;

    int s = s0;
    for (; s + 3 < s1; s += 4) {
        float4 v0 = *(const float4*)(base + (size_t)(s    ) * HH);
        float4 v1 = *(const float4*)(base + (size_t)(s + 1) * HH);
        float4 v2 = *(const float4*)(base + (size_t)(s + 2) * HH);
        float4 v3 = *(const float4*)(base + (size_t)(s + 3) * HH);
        a0.x += v0.x; a0.y += v0.y; a0.z += v0.z; a0.w += v0.w;
        a1.x += v1.x; a1.y += v1.y; a1.z += v1.z; a1.w += v1.w;
        a2.x += v2.x; a2.y += v2.y; a2.z += v2.z; a2.w += v2.w;
        a3.x += v3.x; a3.y += v3.y; a3.z += v3.z; a3.w += v3.w;
    }
    for (; s < s1; ++s) {
        float4 v0 = *(const float4*)(base + (size_t)s * HH);
        a0.x += v0.x; a0.y += v0.y; a0.z += v0.z; a0.w += v0.w;
    }
    float px = a0.x + a1.x + a2.x + a3.x;
    float py = a0.y + a1.y + a2.y + a3.y;
    float pz = a0.z + a1.z + a2.z + a3.z;
    float pw = a0.w + a1.w + a2.w + a3.w;

    const int cnt = s1 - s0;
    const float inv = (cnt > 0) ? (1.0f / (float)cnt) : 0.0f;
    px *= inv; py *= inv; pz *= inv; pw *= inv;

    // dot with W[c][h][l] for this thread's 4 h values
    const float* wp = W + ((size_t)c * HH + col) * LL;
    float l0 = px * wp[0] + py * wp[3] + pz * wp[6] + pw * wp[9];
    float l1 = px * wp[1] + py * wp[4] + pz * wp[7] + pw * wp[10];
    float l2 = px * wp[2] + py * wp[5] + pz * wp[8] + pw * wp[11];

    // wave (64-lane) shuffle reduce
    #pragma unroll
    for (int off = 32; off >= 1; off >>= 1) {
        l0 += __shfl_down(l0, off, 64);
        l1 += __shfl_down(l1, off, 64);
        l2 += __shfl_down(l2, off, 64);
    }
    __shared__ float ws[4][3];
    const int lane = tid & 63, wv = tid >> 6;
    if (lane == 0) { ws[wv][0] = l0; ws[wv][1] = l1; ws[wv][2] = l2; }
    __syncthreads();
    if (tid == 0) {
        float r0 = 0.f, r1 = 0.f, r2 = 0.f;
        #pragma unroll
        for (int w = 0; w < 4; ++w) { r0 += ws[w][0]; r1 += ws[w][1]; r2 += ws[w][2]; }
        logits[bd * LL + 0] = r0 + bias[c * LL + 0];
        logits[bd * LL + 1] = r1 + bias[c * LL + 1];
        logits[bd * LL + 2] = r2 + bias[c * LL + 2];
    }
}

// Single block, 512 threads: one thread per (b,d); log-softmax NLL masked mean.
__global__ __launch_bounds__(512) void loss_kernel(
    const float* __restrict__ logits,   // (BS*DD, L)
    const int*   __restrict__ labels,   // (BS*DD)
    float* __restrict__ out_loss)
{
    const int i = threadIdx.x;   // 0..511 == BS*DD-1
    float nll = 0.f, v = 0.f;
    {
        const int lab = labels[i];
        const float x0 = logits[i * LL + 0];
        const float x1 = logits[i * LL + 1];
        const float x2 = logits[i * LL + 2];
        const float m  = fmaxf(x0, fmaxf(x1, x2));
        const float lse = m + logf(expf(x0 - m) + expf(x1 - m) + expf(x2 - m));
        if (lab >= 0) {
            const float xl = (lab == 0) ? x0 : ((lab == 1) ? x1 : x2);
            nll = lse - xl;
            v   = 1.f;
        }
    }
    #pragma unroll
    for (int off = 32; off >= 1; off >>= 1) {
        nll += __shfl_down(nll, off, 64);
        v   += __shfl_down(v,   off, 64);
    }
    __shared__ float sn[8], sv[8];
    const int lane = i & 63, wv = i >> 6;
    if (lane == 0) { sn[wv] = nll; sv[wv] = v; }
    __syncthreads();
    if (i == 0) {
        float tn = 0.f, tv = 0.f;
        #pragma unroll
        for (int w = 0; w < 8; ++w) { tn += sn[w]; tv += sv[w]; }
        out_loss[0] = (tv > 0.f) ? (tn / tv) : 0.f;
    }
}

extern "C" void kernel_launch(void* const* d_in, const int* in_sizes, int n_in,
                              void* d_out, int out_size, void* d_ws, size_t ws_size,
                              hipStream_t stream) {
    const float* enc   = (const float*)d_in[0];   // (16,2048,1024) f32
    const float* W     = (const float*)d_in[1];   // (8,1024,3) f32
    const float* bias  = (const float*)d_in[2];   // (8,3) f32
    const int*   head  = (const int*)d_in[3];     // (16,32) i32
    const int*   tail  = (const int*)d_in[4];     // (16,32) i32
    const int*   dt    = (const int*)d_in[5];     // (16,32) i32
    const int*   labels= (const int*)d_in[6];     // (16,32) i32
    float* out = (float*)d_out;                   // logits (1536) + loss (1)

    pool_logits_kernel<<<BS * DD, 256, 0, stream>>>(enc, W, bias, head, tail, dt, out);
    loss_kernel<<<1, 512, 0, stream>>>(out, labels, out + BS * DD * LL);
}

// Round 2
// 202.869 us; speedup vs baseline: 1.0039x; 1.0039x over previous
//
#include <hip/hip_runtime.h>
#include <math.h>

#define BS 16
#define SS 2048
#define HH 1024
#define DD 32
#define CC 8
#define LL 3

// One block per (b,d) span. 1024 threads: tid&255 = float4 column group,
// tid>>8 = row group (rows split 4-way for 32 waves/CU occupancy).
__global__ __launch_bounds__(1024) void pool_logits_kernel(
    const float* __restrict__ enc,   // (BS,S,H)
    const float* __restrict__ W,     // (C,H,L)
    const float* __restrict__ bias,  // (C,L)
    const int*   __restrict__ head,  // (BS,D)
    const int*   __restrict__ tail,  // (BS,D)
    const int*   __restrict__ dt,    // (BS,D)
    float* __restrict__ logits)      // (BS,D,L)
{
    const int bd = blockIdx.x;            // 0..BS*DD-1
    const int b  = bd / DD;
    const int s0 = head[bd] + 1;
    const int s1 = tail[bd];
    const int c  = dt[bd];
    const int tid = threadIdx.x;
    const int cg  = tid & 255;            // which float4 of the 1024-wide row
    const int rg  = tid >> 8;             // row group 0..3
    const int col = cg * 4;

    const float* base = enc + ((size_t)b * SS) * HH + col;

    float4 a0 = make_float4(0.f, 0.f, 0.f, 0.f);
    float4 a1 = a0;

    int s = s0 + rg;
    for (; s + 4 < s1; s += 8) {
        float4 v0 = *(const float4*)(base + (size_t)(s    ) * HH);
        float4 v1 = *(const float4*)(base + (size_t)(s + 4) * HH);
        a0.x += v0.x; a0.y += v0.y; a0.z += v0.z; a0.w += v0.w;
        a1.x += v1.x; a1.y += v1.y; a1.z += v1.z; a1.w += v1.w;
    }
    if (s < s1) {
        float4 v0 = *(const float4*)(base + (size_t)s * HH);
        a0.x += v0.x; a0.y += v0.y; a0.z += v0.z; a0.w += v0.w;
    }
    a0.x += a1.x; a0.y += a1.y; a0.z += a1.z; a0.w += a1.w;

    // fold the 4 row groups via LDS
    __shared__ float4 red[1024];          // 16 KB
    red[tid] = a0;
    __syncthreads();

    if (tid < 256) {
        float4 p0 = red[tid];
        float4 p1 = red[tid + 256];
        float4 p2 = red[tid + 512];
        float4 p3 = red[tid + 768];
        float px = p0.x + p1.x + p2.x + p3.x;
        float py = p0.y + p1.y + p2.y + p3.y;
        float pz = p0.z + p1.z + p2.z + p3.z;
        float pw = p0.w + p1.w + p2.w + p3.w;

        const int cnt = s1 - s0;
        const float inv = (cnt > 0) ? (1.0f / (float)cnt) : 0.0f;
        px *= inv; py *= inv; pz *= inv; pw *= inv;

        const float* wp = W + ((size_t)c * HH + col) * LL;
        float l0 = px * wp[0] + py * wp[3] + pz * wp[6] + pw * wp[9];
        float l1 = px * wp[1] + py * wp[4] + pz * wp[7] + pw * wp[10];
        float l2 = px * wp[2] + py * wp[5] + pz * wp[8] + pw * wp[11];

        #pragma unroll
        for (int off = 32; off >= 1; off >>= 1) {
            l0 += __shfl_down(l0, off, 64);
            l1 += __shfl_down(l1, off, 64);
            l2 += __shfl_down(l2, off, 64);
        }
        __shared__ float ws[4][3];
        const int lane = tid & 63, wv = tid >> 6;
        if (lane == 0) { ws[wv][0] = l0; ws[wv][1] = l1; ws[wv][2] = l2; }
        __syncthreads();
        if (tid == 0) {
            float r0 = 0.f, r1 = 0.f, r2 = 0.f;
            #pragma unroll
            for (int w = 0; w < 4; ++w) { r0 += ws[w][0]; r1 += ws[w][1]; r2 += ws[w][2]; }
            logits[bd * LL + 0] = r0 + bias[c * LL + 0];
            logits[bd * LL + 1] = r1 + bias[c * LL + 1];
            logits[bd * LL + 2] = r2 + bias[c * LL + 2];
        }
    }
}

// Single block, 512 threads: one thread per (b,d); log-softmax NLL masked mean.
__global__ __launch_bounds__(512) void loss_kernel(
    const float* __restrict__ logits,   // (BS*DD, L)
    const int*   __restrict__ labels,   // (BS*DD)
    float* __restrict__ out_loss)
{
    const int i = threadIdx.x;   // 0..511 == BS*DD-1
    float nll = 0.f, v = 0.f;
    {
        const int lab = labels[i];
        const float x0 = logits[i * LL + 0];
        const float x1 = logits[i * LL + 1];
        const float x2 = logits[i * LL + 2];
        const float m  = fmaxf(x0, fmaxf(x1, x2));
        const float lse = m + logf(expf(x0 - m) + expf(x1 - m) + expf(x2 - m));
        if (lab >= 0) {
            const float xl = (lab == 0) ? x0 : ((lab == 1) ? x1 : x2);
            nll = lse - xl;
            v   = 1.f;
        }
    }
    #pragma unroll
    for (int off = 32; off >= 1; off >>= 1) {
        nll += __shfl_down(nll, off, 64);
        v   += __shfl_down(v,   off, 64);
    }
    __shared__ float sn[8], sv[8];
    const int lane = i & 63, wv = i >> 6;
    if (lane == 0) { sn[wv] = nll; sv[wv] = v; }
    __syncthreads();
    if (i == 0) {
        float tn = 0.f, tv = 0.f;
        #pragma unroll
        for (int w = 0; w < 8; ++w) { tn += sn[w]; tv += sv[w]; }
        out_loss[0] = (tv > 0.f) ? (tn / tv) : 0.f;
    }
}

extern "C" void kernel_launch(void* const* d_in, const int* in_sizes, int n_in,
                              void* d_out, int out_size, void* d_ws, size_t ws_size,
                              hipStream_t stream) {
    const float* enc   = (const float*)d_in[0];   // (16,2048,1024) f32
    const float* W     = (const float*)d_in[1];   // (8,1024,3) f32
    const float* bias  = (const float*)d_in[2];   // (8,3) f32
    const int*   head  = (const int*)d_in[3];     // (16,32) i32
    const int*   tail  = (const int*)d_in[4];     // (16,32) i32
    const int*   dt    = (const int*)d_in[5];     // (16,32) i32
    const int*   labels= (const int*)d_in[6];     // (16,32) i32
    float* out = (float*)d_out;                   // logits (1536) + loss (1)

    pool_logits_kernel<<<BS * DD, 1024, 0, stream>>>(enc, W, bias, head, tail, dt, out);
    loss_kernel<<<1, 512, 0, stream>>>(out, labels, out + BS * DD * LL);
}